// Round 8
// baseline (101.659 us; speedup 1.0000x reference)
//
#include <hip/hip_runtime.h>
#include <hip/hip_bf16.h>

#define NPIX 8192
#define BATCH 8
#define CCH 128
#define CEMB 64
#define NR 13            // doubling rounds: covers ancestor distance < 8192
#define LCAP 2048        // entry-list / touched-list capacity per batch
#define STHR 69.0f       // s <= 69 <=> w = exp(-s) >= ~1e-30

typedef short bf16x8 __attribute__((ext_vector_type(8)));
typedef float f32x4 __attribute__((ext_vector_type(4)));

__device__ __forceinline__ float b2f(unsigned short h) {
    return __uint_as_float(((unsigned int)h) << 16);
}
__device__ __forceinline__ unsigned short f2b(float f) {   // f32 -> bf16 RNE
    unsigned int u = __float_as_uint(f);
    u = (u + 0x7FFFu + ((u >> 16) & 1u)) >> 16;
    return (unsigned short)u;
}

// ---------------------------------------------------------------------------
// Fused embed + edge-energy via MFMA (split precision, Delta-x formulation):
//   s_right[p] = || W_embed (x[p+1]-x[p]) ||^2
//   s_down [p] = || W_embed (x[p+128]-x[p]) ||^2
// Uses w = exp(-||e_u - e_v||^2) linearity: Delta e = W * Delta x, so e is
// never materialized. Squared-reduce of MFMA D-frags + shfl_xor(16,32).
// Invalid edges (x==127 / last row) produce unused values (tree edges are
// always real grid edges).
// ---------------------------------------------------------------------------
#define EP 64
__global__ void __launch_bounds__(256) k_embedw(
    const float* __restrict__ last_fm,
    const float* __restrict__ W_embed,
    float* __restrict__ sR,     // [B][NPIX]
    float* __restrict__ sD)     // [B][NPIX]
{
    __shared__ unsigned short Whi[CEMB * CCH];   // 16KB, chunk-XOR swizzled rows
    __shared__ unsigned short Wlo[CEMB * CCH];   // 16KB
    __shared__ unsigned short BRhi[16 * EP * 8]; // 8KB  [chunk=c>>3][q][j=c&7]
    __shared__ unsigned short BRlo[16 * EP * 8]; // 8KB
    __shared__ unsigned short BDhi[16 * EP * 8]; // 8KB
    __shared__ unsigned short BDlo[16 * EP * 8]; // 8KB
    const int tid = threadIdx.x;
    const int b = blockIdx.y;
    const int pbase = blockIdx.x * EP;

    for (int i = tid; i < CEMB * CCH; i += 256) {
        const int ce = i >> 7, c = i & 127;
        const float w = W_embed[i];
        const unsigned short h = f2b(w);
        const unsigned short l = f2b(w - b2f(h));
        const int pos = (((c >> 3) ^ (ce & 15)) << 3) | (c & 7);
        Whi[ce * 128 + pos] = h;
        Wlo[ce * 128 + pos] = l;
    }
    const bool haveDown = (pbase < NPIX - 128);
    const bool rowEnd = (pbase & 64) != 0;       // block ends at x==127
    for (int i = tid; i < CCH * (EP / 4); i += 256) {
        const int p4 = i & 15, c = i >> 4;
        const float* src = last_fm + ((size_t)(b * CCH + c)) * NPIX;
        const float4 a = *(const float4*)&src[pbase + p4 * 4];
        const float x5 = (p4 == 15) ? (rowEnd ? 0.f : src[pbase + 64])
                                    : src[pbase + p4 * 4 + 4];
        float dr[4] = {a.y - a.x, a.z - a.y, a.w - a.z, x5 - a.w};
        float dd[4] = {0.f, 0.f, 0.f, 0.f};
        if (haveDown) {
            const float4 g = *(const float4*)&src[pbase + 128 + p4 * 4];
            dd[0] = g.x - a.x; dd[1] = g.y - a.y; dd[2] = g.z - a.z; dd[3] = g.w - a.w;
        }
        const int chunk = c >> 3, j = c & 7;
#pragma unroll
        for (int q = 0; q < 4; ++q) {
            const int idx = (chunk * EP + p4 * 4 + q) * 8 + j;
            unsigned short h = f2b(dr[q]);
            BRhi[idx] = h; BRlo[idx] = f2b(dr[q] - b2f(h));
            h = f2b(dd[q]);
            BDhi[idx] = h; BDlo[idx] = f2b(dd[q] - b2f(h));
        }
    }
    __syncthreads();

    const int lane = tid & 63, wv = tid >> 6;
    f32x4 accr[4], accd[4];
#pragma unroll
    for (int i = 0; i < 4; ++i) {
        accr[i] = (f32x4){0.f, 0.f, 0.f, 0.f};
        accd[i] = (f32x4){0.f, 0.f, 0.f, 0.f};
    }
#pragma unroll
    for (int ks = 0; ks < 4; ++ks) {
        const int chunk = ks * 4 + (lane >> 4);
        const int bidx = (chunk * EP + wv * 16 + (lane & 15)) * 8;
        const bf16x8 brh = *(const bf16x8*)&BRhi[bidx];
        const bf16x8 brl = *(const bf16x8*)&BRlo[bidx];
        const bf16x8 bdh = *(const bf16x8*)&BDhi[bidx];
        const bf16x8 bdl = *(const bf16x8*)&BDlo[bidx];
#pragma unroll
        for (int ot = 0; ot < 4; ++ot) {
            const int ce = ot * 16 + (lane & 15);
            const int aidx = ce * 128 + ((chunk ^ (ce & 15)) << 3);
            const bf16x8 ah = *(const bf16x8*)&Whi[aidx];
            const bf16x8 al = *(const bf16x8*)&Wlo[aidx];
            accr[ot] = __builtin_amdgcn_mfma_f32_16x16x32_bf16(ah, brh, accr[ot], 0, 0, 0);
            accr[ot] = __builtin_amdgcn_mfma_f32_16x16x32_bf16(ah, brl, accr[ot], 0, 0, 0);
            accr[ot] = __builtin_amdgcn_mfma_f32_16x16x32_bf16(al, brh, accr[ot], 0, 0, 0);
            accd[ot] = __builtin_amdgcn_mfma_f32_16x16x32_bf16(ah, bdh, accd[ot], 0, 0, 0);
            accd[ot] = __builtin_amdgcn_mfma_f32_16x16x32_bf16(ah, bdl, accd[ot], 0, 0, 0);
            accd[ot] = __builtin_amdgcn_mfma_f32_16x16x32_bf16(al, bdh, accd[ot], 0, 0, 0);
        }
    }
    float pr = 0.f, pd = 0.f;
#pragma unroll
    for (int ot = 0; ot < 4; ++ot)
#pragma unroll
        for (int r = 0; r < 4; ++r) {
            pr += accr[ot][r] * accr[ot][r];
            pd += accd[ot][r] * accd[ot][r];
        }
    pr += __shfl_xor(pr, 16); pr += __shfl_xor(pr, 32);
    pd += __shfl_xor(pd, 16); pd += __shfl_xor(pd, 32);
    if (lane < 16) {
        const int p = pbase + wv * 16 + lane;
        sR[(size_t)b * NPIX + p] = pr;
        sD[(size_t)b * NPIX + p] = pd;
    }
}

// ---------------------------------------------------------------------------
// Prep (per batch, 1024 thr): w from s-arrays (edge identified by pixel-index
// delta +-1/+-128), thresholded -> compact doubling-entry lists, touched list,
// per-touched (1-w^2), 1/norm, per-pixel dense scale, per-pixel fixidx.
// ---------------------------------------------------------------------------
__global__ void __launch_bounds__(1024) k_prep(
    const int* __restrict__ bfs_order,
    const int* __restrict__ bfs_parent,
    const float* __restrict__ sR,
    const float* __restrict__ sD,
    unsigned int* __restrict__ listKK,   // [B][LCAP]
    float* __restrict__ listW,           // [B][LCAP]
    int* __restrict__ loffg,             // [B][NR+1]
    unsigned int* __restrict__ tKPg,     // [B][LCAP]
    float* __restrict__ tOMWg,           // [B][LCAP]
    float* __restrict__ tRNg,            // [B][LCAP]
    int* __restrict__ tcntg,             // [B]
    float* __restrict__ scaleg,          // [B][NPIX] pixel order
    short* __restrict__ fixidx)          // [B][NPIX] pixel order, -1 default
{
    __shared__ unsigned short anc[NPIX];            // 16KB (in-place doubled)
    __shared__ float Wc[NPIX];                      // 32KB (doubled; later normA)
    __shared__ float w0[NPIX];                      // 32KB persistent weights
    __shared__ unsigned short ordL[NPIX];           // 16KB bfs k -> pixel
    __shared__ unsigned short mk[NPIX];             // 16KB touched marks
    __shared__ unsigned int ssA[1024], ssB[1024];   // 8KB scan scratch
    __shared__ unsigned int eKK[LCAP];              // 8KB entry cache
    __shared__ float eW[LCAP];                      // 8KB
    __shared__ unsigned int tKPc[LCAP];             // 8KB touched cache
    __shared__ int loffL[NR + 1];
    __shared__ int sTot;

    const int b = blockIdx.x, tid = threadIdx.x;
    const int* par = bfs_parent + (size_t)b * NPIX;
    const int* ord = bfs_order + (size_t)b * NPIX;
    const size_t base = (size_t)b * NPIX;

    for (int k = tid; k < NPIX; k += 1024) {
        anc[k] = k ? (unsigned short)par[k] : 0;     // root self-loop
        ordL[k] = (unsigned short)ord[k];
        mk[k] = 0;
        scaleg[base + k] = 1.0f;                     // default dense scale
        fixidx[base + k] = -1;
    }
    if (tid == 0) loffL[0] = 0;
    __syncthreads();
    for (int k = tid; k < NPIX; k += 1024) {
        float w = 0.f;
        if (k) {
            const int u = ordL[k], v = ordL[anc[k]];
            const int d = u - v;
            float s;
            if (d == 1)        s = sR[base + v];
            else if (d == -1)  s = sR[base + u];
            else if (d == 128) s = sD[base + v];
            else               s = sD[base + u];
            w = (s <= STHR) ? __expf(-s) : 0.f;
        }
        Wc[k] = w; w0[k] = w;
    }
    __syncthreads();

    // ---- doubling rounds with compaction (early exit when a round is empty) ----
    int r = 0;
    for (; r < NR; ++r) {
        const int k0 = tid * 8;
        float wv[8]; unsigned short av[8]; unsigned int c = 0;
#pragma unroll
        for (int j = 0; j < 8; ++j) { wv[j] = Wc[k0 + j]; av[j] = anc[k0 + j]; c += (wv[j] != 0.f); }
        ssA[tid] = c; __syncthreads();
        unsigned int *s0 = ssA, *s1 = ssB;
        for (int off = 1; off < 1024; off <<= 1) {
            unsigned int x = s0[tid] + ((tid >= off) ? s0[tid - off] : 0u);
            s1[tid] = x; __syncthreads();
            unsigned int* t = s0; s0 = s1; s1 = t;
        }
        const int total = (int)s0[1023];
        int wpos = loffL[r] + (int)s0[tid] - (int)c;
#pragma unroll
        for (int j = 0; j < 8; ++j) {
            if (wv[j] != 0.f) {
                if (wpos < LCAP) {
                    const unsigned int kk = (unsigned)(k0 + j) | ((unsigned)av[j] << 16);
                    listKK[(size_t)b * LCAP + wpos] = kk;
                    listW[(size_t)b * LCAP + wpos] = wv[j];
                    eKK[wpos] = kk; eW[wpos] = wv[j];
                    mk[k0 + j] = 1; mk[av[j]] = 1;
                }
                ++wpos;
            }
        }
        __syncthreads();
        const int tot = min(total, LCAP - loffL[r]);
        if (tid == 0) loffL[r + 1] = loffL[r] + tot;
        __syncthreads();
        if (tot == 0) { ++r; break; }
        if (r + 1 < NR) {  // in-place doubling: read-phase -> barrier -> write-phase
            unsigned short a2[8]; float w2[8];
#pragma unroll
            for (int j = 0; j < 8; ++j) { const int a = av[j]; w2[j] = wv[j] * Wc[a]; a2[j] = anc[a]; }
            __syncthreads();
#pragma unroll
            for (int j = 0; j < 8; ++j) { Wc[k0 + j] = w2[j]; anc[k0 + j] = a2[j]; }
            __syncthreads();
        }
    }
    if (tid == 0) for (int rr = r; rr < NR; ++rr) loffL[rr + 1] = loffL[r];
    __syncthreads();
    if (tid <= NR) loffg[b * (NR + 1) + tid] = loffL[tid];

    // ---- touched compaction (sorted by k) ----
    {
        const int k0 = tid * 8;
        unsigned short fl[8]; unsigned int c = 0;
#pragma unroll
        for (int j = 0; j < 8; ++j) { fl[j] = mk[k0 + j]; c += fl[j]; }
        ssA[tid] = c; __syncthreads();
        unsigned int *s0 = ssA, *s1 = ssB;
        for (int off = 1; off < 1024; off <<= 1) {
            unsigned int x = s0[tid] + ((tid >= off) ? s0[tid - off] : 0u);
            s1[tid] = x; __syncthreads();
            unsigned int* t = s0; s0 = s1; s1 = t;
        }
        const int total = (int)s0[1023];
        int wpos = (int)s0[tid] - (int)c;
#pragma unroll
        for (int j = 0; j < 8; ++j) {
            if (fl[j]) {
                if (wpos < LCAP) {
                    const unsigned int tp = (unsigned)(k0 + j) | ((unsigned)ordL[k0 + j] << 16);
                    tKPg[(size_t)b * LCAP + wpos] = tp; tKPc[wpos] = tp;
                }
                ++wpos;
            }
        }
        if (tid == 0) { sTot = min(total, LCAP); tcntg[b] = min(total, LCAP); }
        __syncthreads();
    }

    // ---- norm channel sparse simulation (ones vector) ----
    float* normA = Wc;                               // Wc dead, reuse as f32 array
    for (int k = tid; k < NPIX; k += 1024) normA[k] = 1.0f;
    __syncthreads();
    for (int rr = 0; rr < NR; ++rr) {                // UP (ascending chunks)
        const int e0 = loffL[rr], e1 = loffL[rr + 1];
        for (int bb = e0; bb < e1; bb += 1024) {
            const int e = bb + tid; const bool ok = e < e1;
            const unsigned int kk = ok ? eKK[e] : 0u;
            const float W = ok ? eW[e] : 0.f;
            const float a = normA[kk & 0xFFFFu];
            __syncthreads();
            if (W != 0.f) atomicAdd(&normA[kk >> 16], W * a);
            __syncthreads();
        }
    }
    for (int k = tid; k < NPIX; k += 1024) {         // alpha = (1-w^2) * A
        const float w = w0[k];
        normA[k] *= (1.f - w * w);
    }
    __syncthreads();
    for (int rr = 0; rr < NR; ++rr) {                // DOWN (descending chunks)
        const int e0 = loffL[rr], e1 = loffL[rr + 1];
        if (e1 <= e0) continue;
        const int cst = e0 + ((e1 - 1 - e0) / 1024) * 1024;
        for (int bb = cst; bb >= e0; bb -= 1024) {
            const int e = bb + tid; const bool ok = e < e1;
            const unsigned int kk = ok ? eKK[e] : 0u;
            const float W = ok ? eW[e] : 0.f;
            const float va = normA[kk >> 16];
            const float vs = normA[kk & 0xFFFFu];
            __syncthreads();
            if (ok) normA[kk & 0xFFFFu] = fmaf(W, va, vs);
            __syncthreads();
        }
    }
    // ---- per-touched outputs + scale/fixidx overwrite ----
    const int tc = sTot;
    for (int i = tid; i < tc; i += 1024) {
        const unsigned int tp = tKPc[i];
        const int k = (int)(tp & 0xFFFFu), pix = (int)(tp >> 16);
        const float w = w0[k];
        const float omw2 = 1.f - w * w;
        const float rn = 1.f / normA[k];
        tOMWg[(size_t)b * LCAP + i] = omw2;
        tRNg[(size_t)b * LCAP + i] = rn;
        scaleg[base + pix] = omw2 * rn;
        fixidx[base + pix] = (short)i;
    }
}

// ---------------------------------------------------------------------------
// Sparse corrections: per (batch, channel) wave, exact doubling sweeps on
// touched nodes in LDS; emits filt[c] = Y*rn per touched pixel.
// ---------------------------------------------------------------------------
__global__ void __launch_bounds__(256) k_sparse(
    const float* __restrict__ last_fm,
    const unsigned int* __restrict__ listKK,
    const float* __restrict__ listW,
    const int* __restrict__ loffg,
    const unsigned int* __restrict__ tKPg,
    const float* __restrict__ tOMWg,
    const float* __restrict__ tRNg,
    const int* __restrict__ tcntg,
    float* __restrict__ dltg)           // [B][LCAP][CCH] filt values
{
    __shared__ float As[4][NPIX];            // 128KB
    const int lane = threadIdx.x & 63;
    const int wv = threadIdx.x >> 6;
    const int b = blockIdx.x >> 5;
    const int c = (blockIdx.x & 31) * 4 + wv;
    float* A = As[wv];
    const int tc = tcntg[b];
    const unsigned int* tkp = tKPg + (size_t)b * LCAP;
    const float* tom = tOMWg + (size_t)b * LCAP;
    const float* trn = tRNg + (size_t)b * LCAP;
    const unsigned int* lkk = listKK + (size_t)b * LCAP;
    const float* lw = listW + (size_t)b * LCAP;
    const float* src = last_fm + ((size_t)(b * CCH + c)) * NPIX;
    int lo[NR + 1];
#pragma unroll
    for (int i = 0; i <= NR; ++i) lo[i] = loffg[b * (NR + 1) + i];

    for (int i = lane; i < tc; i += 64) {
        const unsigned int tp = tkp[i];
        A[tp & 0xFFFFu] = src[tp >> 16];
    }
    for (int r = 0; r < NR; ++r) {
        for (int e0 = lo[r]; e0 < lo[r + 1]; e0 += 64) {
            const int e = e0 + lane; const bool ok = e < lo[r + 1];
            const unsigned int kk = ok ? lkk[e] : 0u;
            const float W = ok ? lw[e] : 0.f;
            const float a = A[kk & 0xFFFFu];
            if (ok && W != 0.f) atomicAdd(&A[kk >> 16], W * a);
        }
    }
    for (int i = lane; i < tc; i += 64) A[tkp[i] & 0xFFFFu] *= tom[i];
    for (int r = 0; r < NR; ++r) {
        const int e0 = lo[r], e1 = lo[r + 1];
        if (e1 <= e0) continue;
        const int cst = e0 + ((e1 - 1 - e0) / 64) * 64;
        for (int bb = cst; bb >= e0; bb -= 64) {
            const int e = bb + lane; const bool ok = e < e1;
            const unsigned int kk = ok ? lkk[e] : 0u;
            const float W = ok ? lw[e] : 0.f;
            const float va = A[kk >> 16];
            const float vs = A[kk & 0xFFFFu];
            if (ok) A[kk & 0xFFFFu] = fmaf(W, va, vs);
        }
    }
    for (int i = lane; i < tc; i += 64) {
        const unsigned int tp = tkp[i];
        const int k = (int)(tp & 0xFFFFu);
        dltg[((size_t)b * LCAP + i) * CCH + c] = A[k] * trn[i];
    }
}

// ---------------------------------------------------------------------------
// Refine via MFMA: out[o][p] = sum_c Wr[o][c] * bf16(X), where
// X = latent + scale*last_fm for untouched pixels, latent + filt (exact
// sparse value) for touched ones (fixidx lookup, folded before bf16 round).
// ---------------------------------------------------------------------------
#define RP 64
__global__ void __launch_bounds__(256) k_refine(
    const float* __restrict__ last_fm,
    const float* __restrict__ latent,
    const float* __restrict__ scaleg,
    const short* __restrict__ fixidx,
    const float* __restrict__ dltg,
    const float* __restrict__ W_refine,
    float* __restrict__ out)
{
    __shared__ unsigned short Wr[CCH * CCH];     // 32KB
    __shared__ unsigned short XB[16 * RP * 8];   // 16KB
    const int tid = threadIdx.x;
    const int b = blockIdx.y;
    const int pbase = blockIdx.x * RP;

    for (int i = tid; i < CCH * CCH; i += 256) {
        const int o = i >> 7, c = i & 127;
        const int pos = (((c >> 3) ^ (o & 15)) << 3) | (c & 7);
        Wr[o * 128 + pos] = f2b(W_refine[i]);
    }
    for (int i = tid; i < CCH * (RP / 4); i += 256) {
        const int p4 = i & (RP / 4 - 1), c = i / (RP / 4);
        const size_t rb = ((size_t)(b * CCH + c)) * NPIX + pbase + p4 * 4;
        const float4 x = *(const float4*)&last_fm[rb];
        const float4 l = *(const float4*)&latent[rb];
        const float4 s = *(const float4*)&scaleg[(size_t)b * NPIX + pbase + p4 * 4];
        const short4 fi = *(const short4*)&fixidx[(size_t)b * NPIX + pbase + p4 * 4];
        const short fiq[4] = {fi.x, fi.y, fi.z, fi.w};
        const int chunk = c >> 3, j = c & 7;
#pragma unroll
        for (int q = 0; q < 4; ++q) {
            float v;
            if (fiq[q] >= 0)
                v = (&l.x)[q] + dltg[((size_t)b * LCAP + fiq[q]) * CCH + c];
            else
                v = fmaf((&s.x)[q], (&x.x)[q], (&l.x)[q]);
            XB[(chunk * RP + p4 * 4 + q) * 8 + j] = f2b(v);
        }
    }
    __syncthreads();

    const int lane = tid & 63, wv = tid >> 6;
    f32x4 acc[8];
#pragma unroll
    for (int i = 0; i < 8; ++i) acc[i] = (f32x4){0.f, 0.f, 0.f, 0.f};
#pragma unroll
    for (int ks = 0; ks < 4; ++ks) {
        const int chunk = ks * 4 + (lane >> 4);
        const bf16x8 bx = *(const bf16x8*)&XB[(chunk * RP + wv * 16 + (lane & 15)) * 8];
#pragma unroll
        for (int ot = 0; ot < 8; ++ot) {
            const int o = ot * 16 + (lane & 15);
            const bf16x8 aw = *(const bf16x8*)&Wr[o * 128 + ((chunk ^ (o & 15)) << 3)];
            acc[ot] = __builtin_amdgcn_mfma_f32_16x16x32_bf16(aw, bx, acc[ot], 0, 0, 0);
        }
    }
    const int p = pbase + wv * 16 + (lane & 15);
#pragma unroll
    for (int ot = 0; ot < 8; ++ot) {
#pragma unroll
        for (int r = 0; r < 4; ++r) {
            const int o = ot * 16 + (lane >> 4) * 4 + r;
            out[((size_t)(b * CCH + o)) * NPIX + p] = acc[ot][r];
        }
    }
}

extern "C" void kernel_launch(void* const* d_in, const int* in_sizes, int n_in,
                              void* d_out, int out_size, void* d_ws, size_t ws_size,
                              hipStream_t stream)
{
    const float* latent   = (const float*)d_in[0];
    const float* last_fm  = (const float*)d_in[1];
    const float* W_embed  = (const float*)d_in[2];
    const float* W_refine = (const float*)d_in[3];
    const int* bfs_order  = (const int*)d_in[4];
    const int* bfs_parent = (const int*)d_in[5];
    float* out = (float*)d_out;

    char* ws = (char*)d_ws;
    size_t off = 0;
    auto alloc = [&](size_t bytes) -> char* {
        char* p = ws + off;
        off = (off + bytes + 255) & ~(size_t)255;
        return p;
    };
    float* sRg  = (float*)alloc((size_t)BATCH * NPIX * 4);              // 256 KB
    float* sDg  = (float*)alloc((size_t)BATCH * NPIX * 4);              // 256 KB
    unsigned int* listKK = (unsigned int*)alloc((size_t)BATCH * LCAP * 4);
    float* listW = (float*)alloc((size_t)BATCH * LCAP * 4);
    int* loffg = (int*)alloc((size_t)BATCH * (NR + 1) * 4);
    unsigned int* tKPg = (unsigned int*)alloc((size_t)BATCH * LCAP * 4);
    float* tOMWg = (float*)alloc((size_t)BATCH * LCAP * 4);
    float* tRNg = (float*)alloc((size_t)BATCH * LCAP * 4);
    int* tcntg = (int*)alloc((size_t)BATCH * 4);
    float* scaleg = (float*)alloc((size_t)BATCH * NPIX * 4);            // 256 KB
    short* fixg = (short*)alloc((size_t)BATCH * NPIX * 2);              // 128 KB
    float* dltg = (float*)alloc((size_t)BATCH * LCAP * CCH * 4);        // 8.4 MB

    k_embedw<<<dim3(NPIX / EP, BATCH), dim3(256), 0, stream>>>(last_fm, W_embed, sRg, sDg);
    k_prep<<<dim3(BATCH), dim3(1024), 0, stream>>>(bfs_order, bfs_parent, sRg, sDg,
        listKK, listW, loffg, tKPg, tOMWg, tRNg, tcntg, scaleg, fixg);
    k_sparse<<<dim3(BATCH * 32), dim3(256), 0, stream>>>(last_fm,
        listKK, listW, loffg, tKPg, tOMWg, tRNg, tcntg, dltg);
    k_refine<<<dim3(NPIX / RP, BATCH), dim3(256), 0, stream>>>(last_fm, latent, scaleg,
        fixg, dltg, W_refine, out);
}

// Round 9
// 82.565 us; speedup vs baseline: 1.2313x; 1.2313x over previous
//
#include <hip/hip_runtime.h>
#include <hip/hip_bf16.h>

#define NPIX 8192
#define BATCH 8
#define CCH 128
#define CEMB 64
#define NR 13            // doubling rounds: covers ancestor distance < 8192
#define LCAP 2048        // entry-list / touched-list capacity per batch
#define STHR 69.0f       // s <= 69 <=> w = exp(-s) >= ~1e-30

typedef short bf16x8 __attribute__((ext_vector_type(8)));
typedef float f32x4 __attribute__((ext_vector_type(4)));

__device__ __forceinline__ float b2f(unsigned short h) {
    return __uint_as_float(((unsigned int)h) << 16);
}
__device__ __forceinline__ unsigned short f2b(float f) {   // f32 -> bf16 RNE
    unsigned int u = __float_as_uint(f);
    u = (u + 0x7FFFu + ((u >> 16) & 1u)) >> 16;
    return (unsigned short)u;
}

// ---------------------------------------------------------------------------
// Fused embed + edge-energy via MFMA (bf16, Delta-x formulation):
//   s_right[p] = || W_embed (x[p+1]-x[p]) ||^2
//   s_down [p] = || W_embed (x[p+128]-x[p]) ||^2
// e is never materialized (Delta e = W * Delta x). Plain bf16 suffices:
// 1% relative error on s shifts the w=exp(-s) threshold between e^-68 and
// e^-70 — both invisible. Staging: one thread per (chunk,p) writes one
// contiguous b128 (conflict-free); loads coalesced per channel row.
// ---------------------------------------------------------------------------
#define EP 64
__global__ void __launch_bounds__(256) k_embedw(
    const float* __restrict__ last_fm,
    const float* __restrict__ W_embed,
    float* __restrict__ sR,     // [B][NPIX]
    float* __restrict__ sD)     // [B][NPIX]
{
    __shared__ unsigned short Wh[CEMB * CCH];    // 16KB, chunk-XOR swizzled rows
    __shared__ unsigned short BR[16 * EP * 8];   // 16KB  [chunk][p][j]
    __shared__ unsigned short BD[16 * EP * 8];   // 16KB
    const int tid = threadIdx.x;
    const int b = blockIdx.y;
    const int pbase = blockIdx.x * EP;

    for (int i = tid; i < CEMB * CCH; i += 256) {
        const int ce = i >> 7, c = i & 127;
        const int pos = (((c >> 3) ^ (ce & 15)) << 3) | (c & 7);
        Wh[ce * 128 + pos] = f2b(W_embed[i]);
    }
    for (int i = tid; i < 16 * EP; i += 256) {
        const int chunk = i >> 6, p = i & 63;
        const int gp = pbase + p;
        const bool re = (gp & 127) == 127;           // right edge of image row
        const bool hd = gp + 128 < NPIX;             // has down neighbor
        unsigned short r8[8], d8[8];
#pragma unroll
        for (int j = 0; j < 8; ++j) {
            const int c = chunk * 8 + j;
            const float* src = last_fm + ((size_t)(b * CCH + c)) * NPIX;
            const float a = src[gp];
            const float r = re ? a : src[gp + 1];
            const float d = hd ? src[gp + 128] : a;
            r8[j] = f2b(r - a);
            d8[j] = f2b(d - a);
        }
        *(uint4*)&BR[i * 8] = *(const uint4*)r8;
        *(uint4*)&BD[i * 8] = *(const uint4*)d8;
    }
    __syncthreads();

    const int lane = tid & 63, wv = tid >> 6;
    f32x4 ar[4], ad[4];
#pragma unroll
    for (int i = 0; i < 4; ++i) {
        ar[i] = (f32x4){0.f, 0.f, 0.f, 0.f};
        ad[i] = (f32x4){0.f, 0.f, 0.f, 0.f};
    }
#pragma unroll
    for (int ks = 0; ks < 4; ++ks) {
        const int chunk = ks * 4 + (lane >> 4);
        const int bidx = (chunk * EP + wv * 16 + (lane & 15)) * 8;
        const bf16x8 br = *(const bf16x8*)&BR[bidx];
        const bf16x8 bd = *(const bf16x8*)&BD[bidx];
#pragma unroll
        for (int ot = 0; ot < 4; ++ot) {
            const int ce = ot * 16 + (lane & 15);
            const bf16x8 aw = *(const bf16x8*)&Wh[ce * 128 + ((chunk ^ (ce & 15)) << 3)];
            ar[ot] = __builtin_amdgcn_mfma_f32_16x16x32_bf16(aw, br, ar[ot], 0, 0, 0);
            ad[ot] = __builtin_amdgcn_mfma_f32_16x16x32_bf16(aw, bd, ad[ot], 0, 0, 0);
        }
    }
    float pr = 0.f, pd = 0.f;
#pragma unroll
    for (int ot = 0; ot < 4; ++ot)
#pragma unroll
        for (int r = 0; r < 4; ++r) {
            pr += ar[ot][r] * ar[ot][r];
            pd += ad[ot][r] * ad[ot][r];
        }
    pr += __shfl_xor(pr, 16); pr += __shfl_xor(pr, 32);
    pd += __shfl_xor(pd, 16); pd += __shfl_xor(pd, 32);
    if (lane < 16) {
        const int p = pbase + wv * 16 + lane;
        sR[(size_t)b * NPIX + p] = pr;
        sD[(size_t)b * NPIX + p] = pd;
    }
}

// ---------------------------------------------------------------------------
// Prep (per batch, 1024 thr): w from s-arrays (edge identified by pixel-index
// delta +-1/+-128), thresholded -> compact doubling-entry lists, touched list,
// per-touched (1-w^2), 1/norm, per-pixel dense scale, per-pixel fixidx.
// ---------------------------------------------------------------------------
__global__ void __launch_bounds__(1024) k_prep(
    const int* __restrict__ bfs_order,
    const int* __restrict__ bfs_parent,
    const float* __restrict__ sR,
    const float* __restrict__ sD,
    unsigned int* __restrict__ listKK,   // [B][LCAP]
    float* __restrict__ listW,           // [B][LCAP]
    int* __restrict__ loffg,             // [B][NR+1]
    unsigned int* __restrict__ tKPg,     // [B][LCAP]
    float* __restrict__ tOMWg,           // [B][LCAP]
    float* __restrict__ tRNg,            // [B][LCAP]
    int* __restrict__ tcntg,             // [B]
    float* __restrict__ scaleg,          // [B][NPIX] pixel order
    short* __restrict__ fixidx)          // [B][NPIX] pixel order, -1 default
{
    __shared__ unsigned short anc[NPIX];            // 16KB (in-place doubled)
    __shared__ float Wc[NPIX];                      // 32KB (doubled; later normA)
    __shared__ float w0[NPIX];                      // 32KB persistent weights
    __shared__ unsigned short ordL[NPIX];           // 16KB bfs k -> pixel
    __shared__ unsigned short mk[NPIX];             // 16KB touched marks
    __shared__ unsigned int ssA[1024], ssB[1024];   // 8KB scan scratch
    __shared__ unsigned int eKK[LCAP];              // 8KB entry cache
    __shared__ float eW[LCAP];                      // 8KB
    __shared__ unsigned int tKPc[LCAP];             // 8KB touched cache
    __shared__ int loffL[NR + 1];
    __shared__ int sTot;

    const int b = blockIdx.x, tid = threadIdx.x;
    const int* par = bfs_parent + (size_t)b * NPIX;
    const int* ord = bfs_order + (size_t)b * NPIX;
    const size_t base = (size_t)b * NPIX;

    for (int k = tid; k < NPIX; k += 1024) {
        anc[k] = k ? (unsigned short)par[k] : 0;     // root self-loop
        ordL[k] = (unsigned short)ord[k];
        mk[k] = 0;
        scaleg[base + k] = 1.0f;                     // default dense scale
        fixidx[base + k] = -1;
    }
    if (tid == 0) loffL[0] = 0;
    __syncthreads();
    for (int k = tid; k < NPIX; k += 1024) {
        float w = 0.f;
        if (k) {
            const int u = ordL[k], v = ordL[anc[k]];
            const int d = u - v;
            float s;
            if (d == 1)        s = sR[base + v];
            else if (d == -1)  s = sR[base + u];
            else if (d == 128) s = sD[base + v];
            else               s = sD[base + u];
            w = (s <= STHR) ? __expf(-s) : 0.f;
        }
        Wc[k] = w; w0[k] = w;
    }
    __syncthreads();

    // ---- doubling rounds with compaction (early exit when a round is empty) ----
    int r = 0;
    for (; r < NR; ++r) {
        const int k0 = tid * 8;
        float wv[8]; unsigned short av[8]; unsigned int c = 0;
#pragma unroll
        for (int j = 0; j < 8; ++j) { wv[j] = Wc[k0 + j]; av[j] = anc[k0 + j]; c += (wv[j] != 0.f); }
        ssA[tid] = c; __syncthreads();
        unsigned int *s0 = ssA, *s1 = ssB;
        for (int off = 1; off < 1024; off <<= 1) {
            unsigned int x = s0[tid] + ((tid >= off) ? s0[tid - off] : 0u);
            s1[tid] = x; __syncthreads();
            unsigned int* t = s0; s0 = s1; s1 = t;
        }
        const int total = (int)s0[1023];
        int wpos = loffL[r] + (int)s0[tid] - (int)c;
#pragma unroll
        for (int j = 0; j < 8; ++j) {
            if (wv[j] != 0.f) {
                if (wpos < LCAP) {
                    const unsigned int kk = (unsigned)(k0 + j) | ((unsigned)av[j] << 16);
                    listKK[(size_t)b * LCAP + wpos] = kk;
                    listW[(size_t)b * LCAP + wpos] = wv[j];
                    eKK[wpos] = kk; eW[wpos] = wv[j];
                    mk[k0 + j] = 1; mk[av[j]] = 1;
                }
                ++wpos;
            }
        }
        __syncthreads();
        const int tot = min(total, LCAP - loffL[r]);
        if (tid == 0) loffL[r + 1] = loffL[r] + tot;
        __syncthreads();
        if (tot == 0) { ++r; break; }
        if (r + 1 < NR) {  // in-place doubling: read-phase -> barrier -> write-phase
            unsigned short a2[8]; float w2[8];
#pragma unroll
            for (int j = 0; j < 8; ++j) { const int a = av[j]; w2[j] = wv[j] * Wc[a]; a2[j] = anc[a]; }
            __syncthreads();
#pragma unroll
            for (int j = 0; j < 8; ++j) { Wc[k0 + j] = w2[j]; anc[k0 + j] = a2[j]; }
            __syncthreads();
        }
    }
    if (tid == 0) for (int rr = r; rr < NR; ++rr) loffL[rr + 1] = loffL[r];
    __syncthreads();
    if (tid <= NR) loffg[b * (NR + 1) + tid] = loffL[tid];

    // ---- touched compaction (sorted by k) ----
    {
        const int k0 = tid * 8;
        unsigned short fl[8]; unsigned int c = 0;
#pragma unroll
        for (int j = 0; j < 8; ++j) { fl[j] = mk[k0 + j]; c += fl[j]; }
        ssA[tid] = c; __syncthreads();
        unsigned int *s0 = ssA, *s1 = ssB;
        for (int off = 1; off < 1024; off <<= 1) {
            unsigned int x = s0[tid] + ((tid >= off) ? s0[tid - off] : 0u);
            s1[tid] = x; __syncthreads();
            unsigned int* t = s0; s0 = s1; s1 = t;
        }
        const int total = (int)s0[1023];
        int wpos = (int)s0[tid] - (int)c;
#pragma unroll
        for (int j = 0; j < 8; ++j) {
            if (fl[j]) {
                if (wpos < LCAP) {
                    const unsigned int tp = (unsigned)(k0 + j) | ((unsigned)ordL[k0 + j] << 16);
                    tKPg[(size_t)b * LCAP + wpos] = tp; tKPc[wpos] = tp;
                }
                ++wpos;
            }
        }
        if (tid == 0) { sTot = min(total, LCAP); tcntg[b] = min(total, LCAP); }
        __syncthreads();
    }

    // ---- norm channel sparse simulation (ones vector) ----
    float* normA = Wc;                               // Wc dead, reuse as f32 array
    for (int k = tid; k < NPIX; k += 1024) normA[k] = 1.0f;
    __syncthreads();
    for (int rr = 0; rr < NR; ++rr) {                // UP (ascending chunks)
        const int e0 = loffL[rr], e1 = loffL[rr + 1];
        for (int bb = e0; bb < e1; bb += 1024) {
            const int e = bb + tid; const bool ok = e < e1;
            const unsigned int kk = ok ? eKK[e] : 0u;
            const float W = ok ? eW[e] : 0.f;
            const float a = normA[kk & 0xFFFFu];
            __syncthreads();
            if (W != 0.f) atomicAdd(&normA[kk >> 16], W * a);
            __syncthreads();
        }
    }
    for (int k = tid; k < NPIX; k += 1024) {         // alpha = (1-w^2) * A
        const float w = w0[k];
        normA[k] *= (1.f - w * w);
    }
    __syncthreads();
    for (int rr = 0; rr < NR; ++rr) {                // DOWN (descending chunks)
        const int e0 = loffL[rr], e1 = loffL[rr + 1];
        if (e1 <= e0) continue;
        const int cst = e0 + ((e1 - 1 - e0) / 1024) * 1024;
        for (int bb = cst; bb >= e0; bb -= 1024) {
            const int e = bb + tid; const bool ok = e < e1;
            const unsigned int kk = ok ? eKK[e] : 0u;
            const float W = ok ? eW[e] : 0.f;
            const float va = normA[kk >> 16];
            const float vs = normA[kk & 0xFFFFu];
            __syncthreads();
            if (ok) normA[kk & 0xFFFFu] = fmaf(W, va, vs);
            __syncthreads();
        }
    }
    // ---- per-touched outputs + scale/fixidx overwrite ----
    const int tc = sTot;
    for (int i = tid; i < tc; i += 1024) {
        const unsigned int tp = tKPc[i];
        const int k = (int)(tp & 0xFFFFu), pix = (int)(tp >> 16);
        const float w = w0[k];
        const float omw2 = 1.f - w * w;
        const float rn = 1.f / normA[k];
        tOMWg[(size_t)b * LCAP + i] = omw2;
        tRNg[(size_t)b * LCAP + i] = rn;
        scaleg[base + pix] = omw2 * rn;
        fixidx[base + pix] = (short)i;
    }
}

// ---------------------------------------------------------------------------
// Sparse corrections: per (batch, channel) wave, exact doubling sweeps on
// touched nodes in LDS; emits filt[c] = Y*rn per touched pixel.
// ---------------------------------------------------------------------------
__global__ void __launch_bounds__(256) k_sparse(
    const float* __restrict__ last_fm,
    const unsigned int* __restrict__ listKK,
    const float* __restrict__ listW,
    const int* __restrict__ loffg,
    const unsigned int* __restrict__ tKPg,
    const float* __restrict__ tOMWg,
    const float* __restrict__ tRNg,
    const int* __restrict__ tcntg,
    float* __restrict__ dltg)           // [B][LCAP][CCH] filt values
{
    __shared__ float As[4][NPIX];            // 128KB
    const int lane = threadIdx.x & 63;
    const int wv = threadIdx.x >> 6;
    const int b = blockIdx.x >> 5;
    const int c = (blockIdx.x & 31) * 4 + wv;
    float* A = As[wv];
    const int tc = tcntg[b];
    const unsigned int* tkp = tKPg + (size_t)b * LCAP;
    const float* tom = tOMWg + (size_t)b * LCAP;
    const float* trn = tRNg + (size_t)b * LCAP;
    const unsigned int* lkk = listKK + (size_t)b * LCAP;
    const float* lw = listW + (size_t)b * LCAP;
    const float* src = last_fm + ((size_t)(b * CCH + c)) * NPIX;
    int lo[NR + 1];
#pragma unroll
    for (int i = 0; i <= NR; ++i) lo[i] = loffg[b * (NR + 1) + i];

    for (int i = lane; i < tc; i += 64) {
        const unsigned int tp = tkp[i];
        A[tp & 0xFFFFu] = src[tp >> 16];
    }
    for (int r = 0; r < NR; ++r) {
        for (int e0 = lo[r]; e0 < lo[r + 1]; e0 += 64) {
            const int e = e0 + lane; const bool ok = e < lo[r + 1];
            const unsigned int kk = ok ? lkk[e] : 0u;
            const float W = ok ? lw[e] : 0.f;
            const float a = A[kk & 0xFFFFu];
            if (ok && W != 0.f) atomicAdd(&A[kk >> 16], W * a);
        }
    }
    for (int i = lane; i < tc; i += 64) A[tkp[i] & 0xFFFFu] *= tom[i];
    for (int r = 0; r < NR; ++r) {
        const int e0 = lo[r], e1 = lo[r + 1];
        if (e1 <= e0) continue;
        const int cst = e0 + ((e1 - 1 - e0) / 64) * 64;
        for (int bb = cst; bb >= e0; bb -= 64) {
            const int e = bb + lane; const bool ok = e < e1;
            const unsigned int kk = ok ? lkk[e] : 0u;
            const float W = ok ? lw[e] : 0.f;
            const float va = A[kk >> 16];
            const float vs = A[kk & 0xFFFFu];
            if (ok) A[kk & 0xFFFFu] = fmaf(W, va, vs);
        }
    }
    for (int i = lane; i < tc; i += 64) {
        const unsigned int tp = tkp[i];
        const int k = (int)(tp & 0xFFFFu);
        dltg[((size_t)b * LCAP + i) * CCH + c] = A[k] * trn[i];
    }
}

// ---------------------------------------------------------------------------
// Refine via MFMA: out[o][p] = sum_c Wr[o][c] * bf16(X), where
// X = latent + scale*last_fm (untouched) or latent + filt (touched, exact).
// Staging: one thread per (chunk,p), one contiguous b128 write.
// ---------------------------------------------------------------------------
#define RP 64
__global__ void __launch_bounds__(256) k_refine(
    const float* __restrict__ last_fm,
    const float* __restrict__ latent,
    const float* __restrict__ scaleg,
    const short* __restrict__ fixidx,
    const float* __restrict__ dltg,
    const float* __restrict__ W_refine,
    float* __restrict__ out)
{
    __shared__ unsigned short Wr[CCH * CCH];     // 32KB
    __shared__ unsigned short XB[16 * RP * 8];   // 16KB
    const int tid = threadIdx.x;
    const int b = blockIdx.y;
    const int pbase = blockIdx.x * RP;

    for (int i = tid; i < CCH * CCH; i += 256) {
        const int o = i >> 7, c = i & 127;
        const int pos = (((c >> 3) ^ (o & 15)) << 3) | (c & 7);
        Wr[o * 128 + pos] = f2b(W_refine[i]);
    }
    for (int i = tid; i < 16 * RP; i += 256) {
        const int chunk = i >> 6, p = i & 63;
        const int gp = pbase + p;
        const float sc = scaleg[(size_t)b * NPIX + gp];
        const short fi = fixidx[(size_t)b * NPIX + gp];
        unsigned short x8[8];
        if (fi >= 0) {
#pragma unroll
            for (int j = 0; j < 8; ++j) {
                const int c = chunk * 8 + j;
                const float v = latent[((size_t)(b * CCH + c)) * NPIX + gp]
                              + dltg[((size_t)b * LCAP + fi) * CCH + c];
                x8[j] = f2b(v);
            }
        } else {
#pragma unroll
            for (int j = 0; j < 8; ++j) {
                const int c = chunk * 8 + j;
                const size_t rb = ((size_t)(b * CCH + c)) * NPIX + gp;
                x8[j] = f2b(fmaf(sc, last_fm[rb], latent[rb]));
            }
        }
        *(uint4*)&XB[i * 8] = *(const uint4*)x8;
    }
    __syncthreads();

    const int lane = tid & 63, wv = tid >> 6;
    f32x4 acc[8];
#pragma unroll
    for (int i = 0; i < 8; ++i) acc[i] = (f32x4){0.f, 0.f, 0.f, 0.f};
#pragma unroll
    for (int ks = 0; ks < 4; ++ks) {
        const int chunk = ks * 4 + (lane >> 4);
        const bf16x8 bx = *(const bf16x8*)&XB[(chunk * RP + wv * 16 + (lane & 15)) * 8];
#pragma unroll
        for (int ot = 0; ot < 8; ++ot) {
            const int o = ot * 16 + (lane & 15);
            const bf16x8 aw = *(const bf16x8*)&Wr[o * 128 + ((chunk ^ (o & 15)) << 3)];
            acc[ot] = __builtin_amdgcn_mfma_f32_16x16x32_bf16(aw, bx, acc[ot], 0, 0, 0);
        }
    }
    const int p = pbase + wv * 16 + (lane & 15);
#pragma unroll
    for (int ot = 0; ot < 8; ++ot) {
#pragma unroll
        for (int r = 0; r < 4; ++r) {
            const int o = ot * 16 + (lane >> 4) * 4 + r;
            out[((size_t)(b * CCH + o)) * NPIX + p] = acc[ot][r];
        }
    }
}

extern "C" void kernel_launch(void* const* d_in, const int* in_sizes, int n_in,
                              void* d_out, int out_size, void* d_ws, size_t ws_size,
                              hipStream_t stream)
{
    const float* latent   = (const float*)d_in[0];
    const float* last_fm  = (const float*)d_in[1];
    const float* W_embed  = (const float*)d_in[2];
    const float* W_refine = (const float*)d_in[3];
    const int* bfs_order  = (const int*)d_in[4];
    const int* bfs_parent = (const int*)d_in[5];
    float* out = (float*)d_out;

    char* ws = (char*)d_ws;
    size_t off = 0;
    auto alloc = [&](size_t bytes) -> char* {
        char* p = ws + off;
        off = (off + bytes + 255) & ~(size_t)255;
        return p;
    };
    float* sRg  = (float*)alloc((size_t)BATCH * NPIX * 4);              // 256 KB
    float* sDg  = (float*)alloc((size_t)BATCH * NPIX * 4);              // 256 KB
    unsigned int* listKK = (unsigned int*)alloc((size_t)BATCH * LCAP * 4);
    float* listW = (float*)alloc((size_t)BATCH * LCAP * 4);
    int* loffg = (int*)alloc((size_t)BATCH * (NR + 1) * 4);
    unsigned int* tKPg = (unsigned int*)alloc((size_t)BATCH * LCAP * 4);
    float* tOMWg = (float*)alloc((size_t)BATCH * LCAP * 4);
    float* tRNg = (float*)alloc((size_t)BATCH * LCAP * 4);
    int* tcntg = (int*)alloc((size_t)BATCH * 4);
    float* scaleg = (float*)alloc((size_t)BATCH * NPIX * 4);            // 256 KB
    short* fixg = (short*)alloc((size_t)BATCH * NPIX * 2);              // 128 KB
    float* dltg = (float*)alloc((size_t)BATCH * LCAP * CCH * 4);        // 8.4 MB

    k_embedw<<<dim3(NPIX / EP, BATCH), dim3(256), 0, stream>>>(last_fm, W_embed, sRg, sDg);
    k_prep<<<dim3(BATCH), dim3(1024), 0, stream>>>(bfs_order, bfs_parent, sRg, sDg,
        listKK, listW, loffg, tKPg, tOMWg, tRNg, tcntg, scaleg, fixg);
    k_sparse<<<dim3(BATCH * 32), dim3(256), 0, stream>>>(last_fm,
        listKK, listW, loffg, tKPg, tOMWg, tRNg, tcntg, dltg);
    k_refine<<<dim3(NPIX / RP, BATCH), dim3(256), 0, stream>>>(last_fm, latent, scaleg,
        fixg, dltg, W_refine, out);
}

// Round 10
// 73.910 us; speedup vs baseline: 1.3754x; 1.1171x over previous
//
#include <hip/hip_runtime.h>
#include <hip/hip_bf16.h>

#define NPIX 8192
#define BATCH 8
#define CCH 128
#define CEMB 64
#define NR 13            // doubling rounds: covers ancestor distance < 8192
#define LCAP 2048        // entry-list / touched-list capacity per batch
#define STHR 69.0f       // s <= 69 <=> w = exp(-s) >= ~1e-30

typedef short bf16x8 __attribute__((ext_vector_type(8)));
typedef float f32x4 __attribute__((ext_vector_type(4)));

__device__ __forceinline__ float b2f(unsigned short h) {
    return __uint_as_float(((unsigned int)h) << 16);
}
__device__ __forceinline__ unsigned short f2b(float f) {   // f32 -> bf16 RNE
    unsigned int u = __float_as_uint(f);
    u = (u + 0x7FFFu + ((u >> 16) & 1u)) >> 16;
    return (unsigned short)u;
}

// ---------------------------------------------------------------------------
// Fused embed + edge-energy via MFMA (bf16, Delta-x formulation):
//   s_right[p] = || W_embed (x[p+1]-x[p]) ||^2
//   s_down [p] = || W_embed (x[p+128]-x[p]) ||^2
// Staging vectorized: each thread owns (chunk, 4 pixels) -> float4 global
// loads, ONE latency round instead of four. LDS B rows at
// row = p*16 + (chunk ^ (p&15)) -> even bank-group spread for b128 write+read.
// ---------------------------------------------------------------------------
#define EP 64
__global__ void __launch_bounds__(256) k_embedw(
    const float* __restrict__ last_fm,
    const float* __restrict__ W_embed,
    float* __restrict__ sR,     // [B][NPIX]
    float* __restrict__ sD)     // [B][NPIX]
{
    __shared__ unsigned short Wh[CEMB * CCH];    // 16KB, chunk-XOR swizzled rows
    __shared__ unsigned short BR[16 * EP * 8];   // 16KB
    __shared__ unsigned short BD[16 * EP * 8];   // 16KB
    const int tid = threadIdx.x;
    const int b = blockIdx.y;
    const int pbase = blockIdx.x * EP;

    for (int i = tid; i < CEMB * CCH; i += 256) {
        const int ce = i >> 7, c = i & 127;
        const int pos = (((c >> 3) ^ (ce & 15)) << 3) | (c & 7);
        Wh[ce * 128 + pos] = f2b(W_embed[i]);
    }
    {
        const int chunk = tid >> 4, p4 = tid & 15;
        const int gp4 = pbase + p4 * 4;
        const bool hr = gp4 + 4 < NPIX;          // next float4's .x exists
        const bool hd = gp4 + 131 < NPIX;        // down float4 fully in range
        float4 a[8], d[8]; float xn[8];
#pragma unroll
        for (int j = 0; j < 8; ++j) {
            const float* src = last_fm + ((size_t)(b * CCH + chunk * 8 + j)) * NPIX;
            a[j] = *(const float4*)&src[gp4];
            xn[j] = hr ? src[gp4 + 4] : a[j].w;
            d[j] = hd ? *(const float4*)&src[gp4 + 128] : a[j];
        }
#pragma unroll
        for (int q = 0; q < 4; ++q) {
            const int p = p4 * 4 + q;
            const int row = p * 16 + (chunk ^ (p & 15));
            unsigned short r8[8], d8[8];
#pragma unroll
            for (int j = 0; j < 8; ++j) {
                const float aq = (&a[j].x)[q];
                const float rq = (q < 3) ? (&a[j].x)[q + 1] : xn[j];
                r8[j] = f2b(rq - aq);
                d8[j] = f2b((&d[j].x)[q] - aq);
            }
            *(uint4*)&BR[row * 8] = *(const uint4*)r8;
            *(uint4*)&BD[row * 8] = *(const uint4*)d8;
        }
    }
    __syncthreads();

    const int lane = tid & 63, wv = tid >> 6;
    f32x4 ar[4], ad[4];
#pragma unroll
    for (int i = 0; i < 4; ++i) {
        ar[i] = (f32x4){0.f, 0.f, 0.f, 0.f};
        ad[i] = (f32x4){0.f, 0.f, 0.f, 0.f};
    }
    const int pl = wv * 16 + (lane & 15);
#pragma unroll
    for (int ks = 0; ks < 4; ++ks) {
        const int chunk = ks * 4 + (lane >> 4);
        const int row = pl * 16 + (chunk ^ (pl & 15));
        const bf16x8 br = *(const bf16x8*)&BR[row * 8];
        const bf16x8 bd = *(const bf16x8*)&BD[row * 8];
#pragma unroll
        for (int ot = 0; ot < 4; ++ot) {
            const int ce = ot * 16 + (lane & 15);
            const bf16x8 aw = *(const bf16x8*)&Wh[ce * 128 + ((chunk ^ (ce & 15)) << 3)];
            ar[ot] = __builtin_amdgcn_mfma_f32_16x16x32_bf16(aw, br, ar[ot], 0, 0, 0);
            ad[ot] = __builtin_amdgcn_mfma_f32_16x16x32_bf16(aw, bd, ad[ot], 0, 0, 0);
        }
    }
    float pr = 0.f, pd = 0.f;
#pragma unroll
    for (int ot = 0; ot < 4; ++ot)
#pragma unroll
        for (int r = 0; r < 4; ++r) {
            pr += ar[ot][r] * ar[ot][r];
            pd += ad[ot][r] * ad[ot][r];
        }
    pr += __shfl_xor(pr, 16); pr += __shfl_xor(pr, 32);
    pd += __shfl_xor(pd, 16); pd += __shfl_xor(pd, 32);
    if (lane < 16) {
        const int p = pbase + wv * 16 + lane;
        sR[(size_t)b * NPIX + p] = pr;
        sD[(size_t)b * NPIX + p] = pd;
    }
}

// ---------------------------------------------------------------------------
// Prep (per batch, 1024 thr): w from s-arrays (edge identified by pixel-index
// delta +-1/+-128), thresholded -> compact doubling-entry lists, touched list,
// per-touched (1-w^2), 1/norm, per-pixel dense scale, per-pixel fixidx.
// ---------------------------------------------------------------------------
__global__ void __launch_bounds__(1024) k_prep(
    const int* __restrict__ bfs_order,
    const int* __restrict__ bfs_parent,
    const float* __restrict__ sR,
    const float* __restrict__ sD,
    unsigned int* __restrict__ listKK,   // [B][LCAP]
    float* __restrict__ listW,           // [B][LCAP]
    int* __restrict__ loffg,             // [B][NR+1]
    unsigned int* __restrict__ tKPg,     // [B][LCAP]
    float* __restrict__ tOMWg,           // [B][LCAP]
    float* __restrict__ tRNg,            // [B][LCAP]
    int* __restrict__ tcntg,             // [B]
    float* __restrict__ scaleg,          // [B][NPIX] pixel order
    short* __restrict__ fixidx)          // [B][NPIX] pixel order, -1 default
{
    __shared__ unsigned short anc[NPIX];            // 16KB (in-place doubled)
    __shared__ float Wc[NPIX];                      // 32KB (doubled; later normA)
    __shared__ float w0[NPIX];                      // 32KB persistent weights
    __shared__ unsigned short ordL[NPIX];           // 16KB bfs k -> pixel
    __shared__ unsigned short mk[NPIX];             // 16KB touched marks
    __shared__ unsigned int ssA[1024], ssB[1024];   // 8KB scan scratch
    __shared__ unsigned int eKK[LCAP];              // 8KB entry cache
    __shared__ float eW[LCAP];                      // 8KB
    __shared__ unsigned int tKPc[LCAP];             // 8KB touched cache
    __shared__ int loffL[NR + 1];
    __shared__ int sTot;

    const int b = blockIdx.x, tid = threadIdx.x;
    const int* par = bfs_parent + (size_t)b * NPIX;
    const int* ord = bfs_order + (size_t)b * NPIX;
    const size_t base = (size_t)b * NPIX;

    for (int k = tid; k < NPIX; k += 1024) {
        anc[k] = k ? (unsigned short)par[k] : 0;     // root self-loop
        ordL[k] = (unsigned short)ord[k];
        mk[k] = 0;
        scaleg[base + k] = 1.0f;                     // default dense scale
        fixidx[base + k] = -1;
    }
    if (tid == 0) loffL[0] = 0;
    __syncthreads();
    for (int k = tid; k < NPIX; k += 1024) {
        float w = 0.f;
        if (k) {
            const int u = ordL[k], v = ordL[anc[k]];
            const int d = u - v;
            float s;
            if (d == 1)        s = sR[base + v];
            else if (d == -1)  s = sR[base + u];
            else if (d == 128) s = sD[base + v];
            else               s = sD[base + u];
            w = (s <= STHR) ? __expf(-s) : 0.f;
        }
        Wc[k] = w; w0[k] = w;
    }
    __syncthreads();

    // ---- doubling rounds with compaction (early exit when a round is empty) ----
    int r = 0;
    for (; r < NR; ++r) {
        const int k0 = tid * 8;
        float wv[8]; unsigned short av[8]; unsigned int c = 0;
#pragma unroll
        for (int j = 0; j < 8; ++j) { wv[j] = Wc[k0 + j]; av[j] = anc[k0 + j]; c += (wv[j] != 0.f); }
        ssA[tid] = c; __syncthreads();
        unsigned int *s0 = ssA, *s1 = ssB;
        for (int off = 1; off < 1024; off <<= 1) {
            unsigned int x = s0[tid] + ((tid >= off) ? s0[tid - off] : 0u);
            s1[tid] = x; __syncthreads();
            unsigned int* t = s0; s0 = s1; s1 = t;
        }
        const int total = (int)s0[1023];
        int wpos = loffL[r] + (int)s0[tid] - (int)c;
#pragma unroll
        for (int j = 0; j < 8; ++j) {
            if (wv[j] != 0.f) {
                if (wpos < LCAP) {
                    const unsigned int kk = (unsigned)(k0 + j) | ((unsigned)av[j] << 16);
                    listKK[(size_t)b * LCAP + wpos] = kk;
                    listW[(size_t)b * LCAP + wpos] = wv[j];
                    eKK[wpos] = kk; eW[wpos] = wv[j];
                    mk[k0 + j] = 1; mk[av[j]] = 1;
                }
                ++wpos;
            }
        }
        __syncthreads();
        const int tot = min(total, LCAP - loffL[r]);
        if (tid == 0) loffL[r + 1] = loffL[r] + tot;
        __syncthreads();
        if (tot == 0) { ++r; break; }
        if (r + 1 < NR) {  // in-place doubling: read-phase -> barrier -> write-phase
            unsigned short a2[8]; float w2[8];
#pragma unroll
            for (int j = 0; j < 8; ++j) { const int a = av[j]; w2[j] = wv[j] * Wc[a]; a2[j] = anc[a]; }
            __syncthreads();
#pragma unroll
            for (int j = 0; j < 8; ++j) { Wc[k0 + j] = w2[j]; anc[k0 + j] = a2[j]; }
            __syncthreads();
        }
    }
    if (tid == 0) for (int rr = r; rr < NR; ++rr) loffL[rr + 1] = loffL[r];
    __syncthreads();
    if (tid <= NR) loffg[b * (NR + 1) + tid] = loffL[tid];

    // ---- touched compaction (sorted by k) ----
    {
        const int k0 = tid * 8;
        unsigned short fl[8]; unsigned int c = 0;
#pragma unroll
        for (int j = 0; j < 8; ++j) { fl[j] = mk[k0 + j]; c += fl[j]; }
        ssA[tid] = c; __syncthreads();
        unsigned int *s0 = ssA, *s1 = ssB;
        for (int off = 1; off < 1024; off <<= 1) {
            unsigned int x = s0[tid] + ((tid >= off) ? s0[tid - off] : 0u);
            s1[tid] = x; __syncthreads();
            unsigned int* t = s0; s0 = s1; s1 = t;
        }
        const int total = (int)s0[1023];
        int wpos = (int)s0[tid] - (int)c;
#pragma unroll
        for (int j = 0; j < 8; ++j) {
            if (fl[j]) {
                if (wpos < LCAP) {
                    const unsigned int tp = (unsigned)(k0 + j) | ((unsigned)ordL[k0 + j] << 16);
                    tKPg[(size_t)b * LCAP + wpos] = tp; tKPc[wpos] = tp;
                }
                ++wpos;
            }
        }
        if (tid == 0) { sTot = min(total, LCAP); tcntg[b] = min(total, LCAP); }
        __syncthreads();
    }

    // ---- norm channel sparse simulation (ones vector) ----
    float* normA = Wc;                               // Wc dead, reuse as f32 array
    for (int k = tid; k < NPIX; k += 1024) normA[k] = 1.0f;
    __syncthreads();
    for (int rr = 0; rr < NR; ++rr) {                // UP (ascending chunks)
        const int e0 = loffL[rr], e1 = loffL[rr + 1];
        for (int bb = e0; bb < e1; bb += 1024) {
            const int e = bb + tid; const bool ok = e < e1;
            const unsigned int kk = ok ? eKK[e] : 0u;
            const float W = ok ? eW[e] : 0.f;
            const float a = normA[kk & 0xFFFFu];
            __syncthreads();
            if (W != 0.f) atomicAdd(&normA[kk >> 16], W * a);
            __syncthreads();
        }
    }
    for (int k = tid; k < NPIX; k += 1024) {         // alpha = (1-w^2) * A
        const float w = w0[k];
        normA[k] *= (1.f - w * w);
    }
    __syncthreads();
    for (int rr = 0; rr < NR; ++rr) {                // DOWN (descending chunks)
        const int e0 = loffL[rr], e1 = loffL[rr + 1];
        if (e1 <= e0) continue;
        const int cst = e0 + ((e1 - 1 - e0) / 1024) * 1024;
        for (int bb = cst; bb >= e0; bb -= 1024) {
            const int e = bb + tid; const bool ok = e < e1;
            const unsigned int kk = ok ? eKK[e] : 0u;
            const float W = ok ? eW[e] : 0.f;
            const float va = normA[kk >> 16];
            const float vs = normA[kk & 0xFFFFu];
            __syncthreads();
            if (ok) normA[kk & 0xFFFFu] = fmaf(W, va, vs);
            __syncthreads();
        }
    }
    // ---- per-touched outputs + scale/fixidx overwrite ----
    const int tc = sTot;
    for (int i = tid; i < tc; i += 1024) {
        const unsigned int tp = tKPc[i];
        const int k = (int)(tp & 0xFFFFu), pix = (int)(tp >> 16);
        const float w = w0[k];
        const float omw2 = 1.f - w * w;
        const float rn = 1.f / normA[k];
        tOMWg[(size_t)b * LCAP + i] = omw2;
        tRNg[(size_t)b * LCAP + i] = rn;
        scaleg[base + pix] = omw2 * rn;
        fixidx[base + pix] = (short)i;
    }
}

// ---------------------------------------------------------------------------
// Sparse corrections: per (batch, channel) wave, exact doubling sweeps on
// touched nodes in LDS; emits filt[c] = Y*rn per touched pixel.
// ---------------------------------------------------------------------------
__global__ void __launch_bounds__(256) k_sparse(
    const float* __restrict__ last_fm,
    const unsigned int* __restrict__ listKK,
    const float* __restrict__ listW,
    const int* __restrict__ loffg,
    const unsigned int* __restrict__ tKPg,
    const float* __restrict__ tOMWg,
    const float* __restrict__ tRNg,
    const int* __restrict__ tcntg,
    float* __restrict__ dltg)           // [B][LCAP][CCH] filt values
{
    __shared__ float As[4][NPIX];            // 128KB
    const int lane = threadIdx.x & 63;
    const int wv = threadIdx.x >> 6;
    const int b = blockIdx.x >> 5;
    const int c = (blockIdx.x & 31) * 4 + wv;
    float* A = As[wv];
    const int tc = tcntg[b];
    const unsigned int* tkp = tKPg + (size_t)b * LCAP;
    const float* tom = tOMWg + (size_t)b * LCAP;
    const float* trn = tRNg + (size_t)b * LCAP;
    const unsigned int* lkk = listKK + (size_t)b * LCAP;
    const float* lw = listW + (size_t)b * LCAP;
    const float* src = last_fm + ((size_t)(b * CCH + c)) * NPIX;
    int lo[NR + 1];
#pragma unroll
    for (int i = 0; i <= NR; ++i) lo[i] = loffg[b * (NR + 1) + i];

    for (int i = lane; i < tc; i += 64) {
        const unsigned int tp = tkp[i];
        A[tp & 0xFFFFu] = src[tp >> 16];
    }
    for (int r = 0; r < NR; ++r) {
        for (int e0 = lo[r]; e0 < lo[r + 1]; e0 += 64) {
            const int e = e0 + lane; const bool ok = e < lo[r + 1];
            const unsigned int kk = ok ? lkk[e] : 0u;
            const float W = ok ? lw[e] : 0.f;
            const float a = A[kk & 0xFFFFu];
            if (ok && W != 0.f) atomicAdd(&A[kk >> 16], W * a);
        }
    }
    for (int i = lane; i < tc; i += 64) A[tkp[i] & 0xFFFFu] *= tom[i];
    for (int r = 0; r < NR; ++r) {
        const int e0 = lo[r], e1 = lo[r + 1];
        if (e1 <= e0) continue;
        const int cst = e0 + ((e1 - 1 - e0) / 64) * 64;
        for (int bb = cst; bb >= e0; bb -= 64) {
            const int e = bb + lane; const bool ok = e < e1;
            const unsigned int kk = ok ? lkk[e] : 0u;
            const float W = ok ? lw[e] : 0.f;
            const float va = A[kk >> 16];
            const float vs = A[kk & 0xFFFFu];
            if (ok) A[kk & 0xFFFFu] = fmaf(W, va, vs);
        }
    }
    for (int i = lane; i < tc; i += 64) {
        const unsigned int tp = tkp[i];
        const int k = (int)(tp & 0xFFFFu);
        dltg[((size_t)b * LCAP + i) * CCH + c] = A[k] * trn[i];
    }
}

// ---------------------------------------------------------------------------
// Refine via MFMA: out[o][p] = sum_c Wr[o][c] * bf16(X), where
// X = latent + scale*last_fm (untouched) or latent + filt (touched, exact).
// Staging vectorized: thread owns (chunk, 4 pixels) -> float4 loads, one
// latency round; XB rows at p*16 + (chunk^(p&15)).
// ---------------------------------------------------------------------------
#define RP 64
__global__ void __launch_bounds__(256) k_refine(
    const float* __restrict__ last_fm,
    const float* __restrict__ latent,
    const float* __restrict__ scaleg,
    const short* __restrict__ fixidx,
    const float* __restrict__ dltg,
    const float* __restrict__ W_refine,
    float* __restrict__ out)
{
    __shared__ unsigned short Wr[CCH * CCH];     // 32KB
    __shared__ unsigned short XB[16 * RP * 8];   // 16KB
    const int tid = threadIdx.x;
    const int b = blockIdx.y;
    const int pbase = blockIdx.x * RP;

    for (int i = tid; i < CCH * CCH; i += 256) {
        const int o = i >> 7, c = i & 127;
        const int pos = (((c >> 3) ^ (o & 15)) << 3) | (c & 7);
        Wr[o * 128 + pos] = f2b(W_refine[i]);
    }
    {
        const int chunk = tid >> 4, p4 = tid & 15;
        const int gp4 = pbase + p4 * 4;
        const float4 sc4 = *(const float4*)&scaleg[(size_t)b * NPIX + gp4];
        const short4 fi4 = *(const short4*)&fixidx[(size_t)b * NPIX + gp4];
        float4 l[8], x[8];
#pragma unroll
        for (int j = 0; j < 8; ++j) {
            const size_t rb = ((size_t)(b * CCH + chunk * 8 + j)) * NPIX + gp4;
            l[j] = *(const float4*)&latent[rb];
            x[j] = *(const float4*)&last_fm[rb];
        }
        const short fiq[4] = {fi4.x, fi4.y, fi4.z, fi4.w};
#pragma unroll
        for (int q = 0; q < 4; ++q) {
            const int p = p4 * 4 + q;
            const int row = p * 16 + (chunk ^ (p & 15));
            unsigned short x8[8];
            if (fiq[q] >= 0) {
#pragma unroll
                for (int j = 0; j < 8; ++j)
                    x8[j] = f2b((&l[j].x)[q]
                              + dltg[((size_t)b * LCAP + fiq[q]) * CCH + chunk * 8 + j]);
            } else {
#pragma unroll
                for (int j = 0; j < 8; ++j)
                    x8[j] = f2b(fmaf((&sc4.x)[q], (&x[j].x)[q], (&l[j].x)[q]));
            }
            *(uint4*)&XB[row * 8] = *(const uint4*)x8;
        }
    }
    __syncthreads();

    const int lane = tid & 63, wv = tid >> 6;
    f32x4 acc[8];
#pragma unroll
    for (int i = 0; i < 8; ++i) acc[i] = (f32x4){0.f, 0.f, 0.f, 0.f};
    const int pl = wv * 16 + (lane & 15);
#pragma unroll
    for (int ks = 0; ks < 4; ++ks) {
        const int chunk = ks * 4 + (lane >> 4);
        const int row = pl * 16 + (chunk ^ (pl & 15));
        const bf16x8 bx = *(const bf16x8*)&XB[row * 8];
#pragma unroll
        for (int ot = 0; ot < 8; ++ot) {
            const int o = ot * 16 + (lane & 15);
            const bf16x8 aw = *(const bf16x8*)&Wr[o * 128 + ((chunk ^ (o & 15)) << 3)];
            acc[ot] = __builtin_amdgcn_mfma_f32_16x16x32_bf16(aw, bx, acc[ot], 0, 0, 0);
        }
    }
    const int p = pbase + wv * 16 + (lane & 15);
#pragma unroll
    for (int ot = 0; ot < 8; ++ot) {
#pragma unroll
        for (int r = 0; r < 4; ++r) {
            const int o = ot * 16 + (lane >> 4) * 4 + r;
            out[((size_t)(b * CCH + o)) * NPIX + p] = acc[ot][r];
        }
    }
}

extern "C" void kernel_launch(void* const* d_in, const int* in_sizes, int n_in,
                              void* d_out, int out_size, void* d_ws, size_t ws_size,
                              hipStream_t stream)
{
    const float* latent   = (const float*)d_in[0];
    const float* last_fm  = (const float*)d_in[1];
    const float* W_embed  = (const float*)d_in[2];
    const float* W_refine = (const float*)d_in[3];
    const int* bfs_order  = (const int*)d_in[4];
    const int* bfs_parent = (const int*)d_in[5];
    float* out = (float*)d_out;

    char* ws = (char*)d_ws;
    size_t off = 0;
    auto alloc = [&](size_t bytes) -> char* {
        char* p = ws + off;
        off = (off + bytes + 255) & ~(size_t)255;
        return p;
    };
    float* sRg  = (float*)alloc((size_t)BATCH * NPIX * 4);              // 256 KB
    float* sDg  = (float*)alloc((size_t)BATCH * NPIX * 4);              // 256 KB
    unsigned int* listKK = (unsigned int*)alloc((size_t)BATCH * LCAP * 4);
    float* listW = (float*)alloc((size_t)BATCH * LCAP * 4);
    int* loffg = (int*)alloc((size_t)BATCH * (NR + 1) * 4);
    unsigned int* tKPg = (unsigned int*)alloc((size_t)BATCH * LCAP * 4);
    float* tOMWg = (float*)alloc((size_t)BATCH * LCAP * 4);
    float* tRNg = (float*)alloc((size_t)BATCH * LCAP * 4);
    int* tcntg = (int*)alloc((size_t)BATCH * 4);
    float* scaleg = (float*)alloc((size_t)BATCH * NPIX * 4);            // 256 KB
    short* fixg = (short*)alloc((size_t)BATCH * NPIX * 2);              // 128 KB
    float* dltg = (float*)alloc((size_t)BATCH * LCAP * CCH * 4);        // 8.4 MB

    k_embedw<<<dim3(NPIX / EP, BATCH), dim3(256), 0, stream>>>(last_fm, W_embed, sRg, sDg);
    k_prep<<<dim3(BATCH), dim3(1024), 0, stream>>>(bfs_order, bfs_parent, sRg, sDg,
        listKK, listW, loffg, tKPg, tOMWg, tRNg, tcntg, scaleg, fixg);
    k_sparse<<<dim3(BATCH * 32), dim3(256), 0, stream>>>(last_fm,
        listKK, listW, loffg, tKPg, tOMWg, tRNg, tcntg, dltg);
    k_refine<<<dim3(NPIX / RP, BATCH), dim3(256), 0, stream>>>(last_fm, latent, scaleg,
        fixg, dltg, W_refine, out);
}